// Round 2
// baseline (520.860 us; speedup 1.0000x reference)
//
#include <hip/hip_runtime.h>
#include <stdint.h>
#include <math.h>

#define IN_DIM 128
#define H_HEADS 8
#define HD 16

typedef __attribute__((ext_vector_type(8))) short bf16x8;
typedef __attribute__((ext_vector_type(4))) float f32x4;

__device__ __forceinline__ unsigned short f2bf_rne(float f) {
    unsigned int u = __float_as_uint(f);
    unsigned int r = (u + 0x7fffu + ((u >> 16) & 1u)) >> 16;
    return (unsigned short)r;
}
__device__ __forceinline__ float bf2f(unsigned short h) {
    return __uint_as_float(((unsigned int)h) << 16);
}

// ---------- prep: transpose + hi/lo split of W matrices, copy biases ----------
// grid 5 blocks: p=0..3 -> Wq,Wk,Wv,Wskip ([8][128][16] -> Wt[c][k], c=h*16+d)
//                p=4    -> Wo ([128][128] k-major -> Wt[c][k])
__global__ __launch_bounds__(256)
void prep_kernel(const float* __restrict__ Wq, const float* __restrict__ Wk,
                 const float* __restrict__ Wv, const float* __restrict__ Wsk,
                 const float* __restrict__ Wo,
                 const float* __restrict__ bq, const float* __restrict__ bk,
                 const float* __restrict__ bv, const float* __restrict__ bsk,
                 unsigned short* __restrict__ WtH, unsigned short* __restrict__ WtL,
                 float* __restrict__ bias_cat)
{
    const int p = blockIdx.x;
    const int t = threadIdx.x;
    const float* src = (p == 0) ? Wq : (p == 1) ? Wk : (p == 2) ? Wv : (p == 3) ? Wsk : Wo;
    unsigned short* dh = WtH + (size_t)p * 16384;
    unsigned short* dl = WtL + (size_t)p * 16384;
#pragma unroll
    for (int j = 0; j < 64; ++j) {
        int o = t + j * 256;            // o = c*128 + k
        int c = o >> 7, k = o & 127;
        float v;
        if (p < 4) {
            int h = c >> 4, d = c & 15;
            v = src[(size_t)h * 2048 + (size_t)k * 16 + d];
        } else {
            v = src[(size_t)k * 128 + c];
        }
        unsigned short hi = f2bf_rne(v);
        unsigned short lo = f2bf_rne(v - bf2f(hi));
        dh[o] = hi; dl[o] = lo;
    }
    if (p < 4 && t < 128) {
        const float* b = (p == 0) ? bq : (p == 1) ? bk : (p == 2) ? bv : bsk;
        bias_cat[p * 128 + t] = b[t];
    }
}

// ---------- split-bf16 MFMA GEMM: out[p] = A @ Wt[p]^T + bias[p] (+res) ----------
// A: [N][128] f32.  Wt: [c][k] bf16 hi/lo (c = output col).  Tile 128 rows x 128 cols.
// block 256 = 4 waves; wave w computes rows w*32..w*32+31, all 128 cols.
template <bool ADD_RES>
__global__ __launch_bounds__(256)
void gemm128_kernel(const float* __restrict__ A,
                    const unsigned short* __restrict__ BtH_base,
                    const unsigned short* __restrict__ BtL_base,
                    const float* __restrict__ bias_base,
                    const float* __restrict__ res,
                    float* __restrict__ out_base, int N)
{
    __shared__ unsigned short AhS[128 * 128];
    __shared__ unsigned short AlS[128 * 128];
    const int t = threadIdx.x;
    const int p = blockIdx.y;
    const int r0 = blockIdx.x * 128;
    const unsigned short* BtH = BtH_base + (size_t)p * 16384;
    const unsigned short* BtL = BtL_base + (size_t)p * 16384;
    const float* bias = bias_base + (size_t)p * 128;
    float* outp = out_base + (size_t)p * N * 128;

    // stage A tile: f32 -> hi/lo bf16, XOR-swizzled rows
#pragma unroll
    for (int j = 0; j < 16; ++j) {
        int f = t + j * 256;
        int row = f >> 5;
        int col4 = (f & 31) << 2;       // float index, multiple of 4
        float4 v = make_float4(0.f, 0.f, 0.f, 0.f);
        int gr = r0 + row;
        if (gr < N) v = *reinterpret_cast<const float4*>(A + (size_t)gr * 128 + col4);
        ushort4 hi, lo;
        hi.x = f2bf_rne(v.x); lo.x = f2bf_rne(v.x - bf2f(hi.x));
        hi.y = f2bf_rne(v.y); lo.y = f2bf_rne(v.y - bf2f(hi.y));
        hi.z = f2bf_rne(v.z); lo.z = f2bf_rne(v.z - bf2f(hi.z));
        hi.w = f2bf_rne(v.w); lo.w = f2bf_rne(v.w - bf2f(hi.w));
        int byte = (col4 * 2) ^ ((row & 7) << 4);     // swizzle 16B slots within row
        *reinterpret_cast<ushort4*>((char*)AhS + row * 256 + byte) = hi;
        *reinterpret_cast<ushort4*>((char*)AlS + row * 256 + byte) = lo;
    }
    __syncthreads();

    const int lane = t & 63;
    const int w = t >> 6;               // wave id 0..3
    const int wrow0 = w * 32;
    const int lr = lane & 15;           // fragment row/col index
    const int lk = lane >> 4;           // k-group 0..3

    f32x4 acc[2][8];
#pragma unroll
    for (int mi = 0; mi < 2; ++mi)
#pragma unroll
        for (int ni = 0; ni < 8; ++ni) acc[mi][ni] = (f32x4){0.f, 0.f, 0.f, 0.f};

#pragma unroll
    for (int ks = 0; ks < 4; ++ks) {
        bf16x8 ah[2], al[2];
#pragma unroll
        for (int mi = 0; mi < 2; ++mi) {
            int row = wrow0 + mi * 16 + lr;
            int byte = (ks * 64 + lk * 16) ^ ((row & 7) << 4);
            ah[mi] = *reinterpret_cast<const bf16x8*>((const char*)AhS + row * 256 + byte);
            al[mi] = *reinterpret_cast<const bf16x8*>((const char*)AlS + row * 256 + byte);
        }
        bf16x8 bh[8], bl[8];
#pragma unroll
        for (int ni = 0; ni < 8; ++ni) {
            int c = ni * 16 + lr;
            size_t goff = (size_t)c * 128 + ks * 32 + lk * 8;
            bh[ni] = *reinterpret_cast<const bf16x8*>(BtH + goff);
            bl[ni] = *reinterpret_cast<const bf16x8*>(BtL + goff);
        }
#pragma unroll
        for (int mi = 0; mi < 2; ++mi)
#pragma unroll
            for (int ni = 0; ni < 8; ++ni) {
                acc[mi][ni] = __builtin_amdgcn_mfma_f32_16x16x32_bf16(ah[mi], bh[ni], acc[mi][ni], 0, 0, 0);
                acc[mi][ni] = __builtin_amdgcn_mfma_f32_16x16x32_bf16(ah[mi], bl[ni], acc[mi][ni], 0, 0, 0);
                acc[mi][ni] = __builtin_amdgcn_mfma_f32_16x16x32_bf16(al[mi], bh[ni], acc[mi][ni], 0, 0, 0);
            }
    }

    // epilogue: C[row][col] = acc + bias[col] (+ res[row][col])
#pragma unroll
    for (int mi = 0; mi < 2; ++mi) {
#pragma unroll
        for (int ni = 0; ni < 8; ++ni) {
            int col = ni * 16 + lr;
            float bc = bias[col];
            int rowbase = wrow0 + mi * 16 + lk * 4;
#pragma unroll
            for (int r = 0; r < 4; ++r) {
                int gr = r0 + rowbase + r;
                if (gr < N) {
                    float val = acc[mi][ni][r] + bc;
                    if (ADD_RES) val += res[(size_t)gr * 128 + col];
                    outp[(size_t)gr * 128 + col] = val;
                }
            }
        }
    }
}

// ---------------- degree histogram ----------------
__global__ void count_kernel(const int* __restrict__ ei, int* __restrict__ deg, int E)
{
    int e = blockIdx.x * 256 + threadIdx.x;
    if (e < E) atomicAdd(&deg[ei[E + e]], 1);   // dst row
}

// ---------------- exclusive scan (single block, shfl-based) ----------------
__global__ __launch_bounds__(1024)
void scan_kernel(const int* __restrict__ deg, int* __restrict__ offs,
                 int* __restrict__ cursor, int N)
{
    __shared__ int wsum[16];
    __shared__ int chunk_total_s;
    const int t = threadIdx.x;
    const int lane = t & 63, wid = t >> 6;
    int running = 0;
    for (int base = 0; base < N; base += 4096) {
        int v[4];
        int idx = base + t * 4;
#pragma unroll
        for (int j = 0; j < 4; ++j) { int i = idx + j; v[j] = (i < N) ? deg[i] : 0; }
        int ls = v[0] + v[1] + v[2] + v[3];
        int inc = ls;
#pragma unroll
        for (int off = 1; off < 64; off <<= 1) {
            int y = __shfl_up(inc, off);
            if (lane >= off) inc += y;
        }
        if (lane == 63) wsum[wid] = inc;
        __syncthreads();
        if (t < 16) {
            int winc = wsum[t];
            for (int off = 1; off < 16; off <<= 1) {
                int y = __shfl_up(winc, off);
                if (t >= off) winc += y;
            }
            wsum[t] = winc;
            if (t == 15) chunk_total_s = winc;
        }
        __syncthreads();
        int wexcl = (wid == 0) ? 0 : wsum[wid - 1];
        int texcl = running + wexcl + (inc - ls);
        int pre = 0;
#pragma unroll
        for (int j = 0; j < 4; ++j) {
            int i = idx + j;
            if (i < N) { offs[i] = texcl + pre; cursor[i] = texcl + pre; }
            pre += v[j];
        }
        running += chunk_total_s;
        __syncthreads();
    }
    if (t == 0) offs[N] = running;
}

// ---------------- scatter edges into CSR ----------------
__global__ void scatter_kernel(const int* __restrict__ ei, const float* __restrict__ ea,
                               int* __restrict__ cursor, int* __restrict__ csr_src,
                               float* __restrict__ csr_ea, int E)
{
    int e = blockIdx.x * 256 + threadIdx.x;
    if (e < E) {
        int s = ei[e], d = ei[E + e];
        int pos = atomicAdd(&cursor[d], 1);
        csr_src[pos] = s;
        csr_ea[pos]  = ea[e];
    }
}

// ---------------- per-node online-softmax attention + aggregation ----------------
// one wave per node: 64 lanes = 8 heads x 8 lanes, 2 dims per lane (col = 2*lane)
__global__ __launch_bounds__(256)
void agg_kernel(const float* __restrict__ qkvs, const int* __restrict__ offs,
                const int* __restrict__ csr_src, const float* __restrict__ csr_ea,
                const float* __restrict__ We, float* __restrict__ heads_cat, int N)
{
    const int lane = threadIdx.x & 63;
    const int node = blockIdx.x * 4 + (threadIdx.x >> 6);
    if (node >= N) return;
    const float* qb = qkvs;
    const float* kb = qkvs + (size_t)N * 128;
    const float* vb = qkvs + (size_t)2 * N * 128;
    const float* sb = qkvs + (size_t)3 * N * 128;

    const float2 q2  = *reinterpret_cast<const float2*>(qb + (size_t)node * 128 + 2 * lane);
    const float2 we2 = *reinterpret_cast<const float2*>(We + 2 * lane);

    float m = -__builtin_huge_valf();
    float ssum = 0.f, a0 = 0.f, a1 = 0.f;
    const int e0 = offs[node], e1 = offs[node + 1];
    for (int i = e0; i < e1; ++i) {
        const int   src = csr_src[i];
        const float eav = csr_ea[i];
        const float2 k2 = *reinterpret_cast<const float2*>(kb + (size_t)src * 128 + 2 * lane);
        const float2 v2 = *reinterpret_cast<const float2*>(vb + (size_t)src * 128 + 2 * lane);
        float ke0 = k2.x + eav * we2.x;
        float ke1 = k2.y + eav * we2.y;
        float dot = q2.x * ke0 + q2.y * ke1;
        dot += __shfl_xor(dot, 1);
        dot += __shfl_xor(dot, 2);
        dot += __shfl_xor(dot, 4);
        float alpha = dot * 0.25f;               // 1/sqrt(16)
        float nm = fmaxf(m, alpha);
        float sc = __expf(m - nm);               // m=-inf first iter -> 0
        float pv = __expf(alpha - nm);
        ssum = ssum * sc + pv;
        a0 = a0 * sc + pv * (v2.x + eav * we2.x);
        a1 = a1 * sc + pv * (v2.y + eav * we2.y);
        m = nm;
    }
    float inv = 1.0f / fmaxf(ssum, 1e-16f);
    const float2 sk = *reinterpret_cast<const float2*>(sb + (size_t)node * 128 + 2 * lane);
    float2 o;
    o.x = a0 * inv + sk.x;
    o.y = a1 * inv + sk.y;
    *reinterpret_cast<float2*>(heads_cat + (size_t)node * 128 + 2 * lane) = o;
}

// ---------------- LayerNorm: wave per node ----------------
__global__ __launch_bounds__(256)
void ln_kernel(const float* __restrict__ pre, const float* __restrict__ gamma,
               const float* __restrict__ beta, float* __restrict__ out, int N)
{
    const int lane = threadIdx.x & 63;
    const int node = blockIdx.x * 4 + (threadIdx.x >> 6);
    if (node >= N) return;
    float v0 = pre[(size_t)node * 128 + lane];
    float v1 = pre[(size_t)node * 128 + 64 + lane];
    float s = v0 + v1;
#pragma unroll
    for (int off = 1; off < 64; off <<= 1) s += __shfl_xor(s, off);
    float mean = s * (1.0f / 128.0f);
    float d0 = v0 - mean, d1 = v1 - mean;
    float sq = d0 * d0 + d1 * d1;
#pragma unroll
    for (int off = 1; off < 64; off <<= 1) sq += __shfl_xor(sq, off);
    float varv = sq * (1.0f / 128.0f);
    float inv = rsqrtf(varv + 1e-5f);
    out[(size_t)node * 128 + lane]      = d0 * inv * gamma[lane] + beta[lane];
    out[(size_t)node * 128 + 64 + lane] = d1 * inv * gamma[lane + 64] + beta[lane + 64];
}

extern "C" void kernel_launch(void* const* d_in, const int* in_sizes, int n_in,
                              void* d_out, int out_size, void* d_ws, size_t ws_size,
                              hipStream_t stream)
{
    const float* x    = (const float*)d_in[0];
    const int*   ei   = (const int*)d_in[1];
    const float* ea   = (const float*)d_in[2];
    const float* Wq   = (const float*)d_in[3];
    const float* bq   = (const float*)d_in[4];
    const float* Wk   = (const float*)d_in[5];
    const float* bk   = (const float*)d_in[6];
    const float* Wv   = (const float*)d_in[7];
    const float* bv   = (const float*)d_in[8];
    const float* We   = (const float*)d_in[9];
    const float* Wsk  = (const float*)d_in[10];
    const float* bsk  = (const float*)d_in[11];
    const float* Wo   = (const float*)d_in[12];
    const float* bo   = (const float*)d_in[13];
    const float* gamma= (const float*)d_in[14];
    const float* beta = (const float*)d_in[15];
    const int N = in_sizes[0] / 128;
    const int E = in_sizes[1] / 2;
    float* out = (float*)d_out;

    char* w = (char*)d_ws;
    float* qkvs      = (float*)w; w += (size_t)4 * N * 128 * sizeof(float);
    float* heads_cat = (float*)w; w += (size_t)N * 128 * sizeof(float);
    float* pre       = (float*)w; w += (size_t)N * 128 * sizeof(float);
    int*   deg       = (int*)w;   w += ((size_t)N + 16) * sizeof(int);
    int*   offs      = (int*)w;   w += ((size_t)N + 16) * sizeof(int);
    int*   cursor    = (int*)w;   w += ((size_t)N + 16) * sizeof(int);
    int*   csr_src   = (int*)w;   w += (size_t)E * sizeof(int);
    float* csr_ea    = (float*)w; w += (size_t)E * sizeof(float);
    unsigned short* WtH = (unsigned short*)w; w += (size_t)5 * 16384 * sizeof(unsigned short);
    unsigned short* WtL = (unsigned short*)w; w += (size_t)5 * 16384 * sizeof(unsigned short);
    float* bias_cat  = (float*)w; w += 4 * 128 * sizeof(float);

    hipMemsetAsync(deg, 0, (size_t)N * sizeof(int), stream);

    prep_kernel<<<5, 256, 0, stream>>>(Wq, Wk, Wv, Wsk, Wo, bq, bk, bv, bsk, WtH, WtL, bias_cat);

    const int gx = (N + 127) / 128;
    dim3 gProj(gx, 4);
    gemm128_kernel<false><<<gProj, 256, 0, stream>>>(x, WtH, WtL, bias_cat, nullptr, qkvs, N);

    count_kernel<<<(E + 255) / 256, 256, 0, stream>>>(ei, deg, E);
    scan_kernel<<<1, 1024, 0, stream>>>(deg, offs, cursor, N);
    scatter_kernel<<<(E + 255) / 256, 256, 0, stream>>>(ei, ea, cursor, csr_src, csr_ea, E);
    agg_kernel<<<(N + 3) / 4, 256, 0, stream>>>(qkvs, offs, csr_src, csr_ea, We, heads_cat, N);

    dim3 gOut(gx, 1);
    gemm128_kernel<true><<<gOut, 256, 0, stream>>>(heads_cat, WtH + (size_t)4 * 16384, WtL + (size_t)4 * 16384,
                                                   bo, x, pre, N);
    ln_kernel<<<(N + 3) / 4, 256, 0, stream>>>(pre, gamma, beta, out, N);
}

// Round 3
// 451.552 us; speedup vs baseline: 1.1535x; 1.1535x over previous
//
#include <hip/hip_runtime.h>
#include <stdint.h>
#include <math.h>

#define IN_DIM 128
#define H_HEADS 8
#define HD 16

typedef __attribute__((ext_vector_type(8))) short bf16x8;
typedef __attribute__((ext_vector_type(4))) float f32x4;

__device__ __forceinline__ unsigned short f2bf_rne(float f) {
    unsigned int u = __float_as_uint(f);
    unsigned int r = (u + 0x7fffu + ((u >> 16) & 1u)) >> 16;
    return (unsigned short)r;
}
__device__ __forceinline__ float bf2f(unsigned short h) {
    return __uint_as_float(((unsigned int)h) << 16);
}

// ---------- prep (5 blocks): transpose + hi/lo split of W, biases ----------
// ---------- + count (remaining blocks): dst-degree histogram ----------
__global__ __launch_bounds__(256)
void prep_count_kernel(const float* __restrict__ Wq, const float* __restrict__ Wk,
                       const float* __restrict__ Wv, const float* __restrict__ Wsk,
                       const float* __restrict__ Wo,
                       const float* __restrict__ bq, const float* __restrict__ bk,
                       const float* __restrict__ bv, const float* __restrict__ bsk,
                       unsigned short* __restrict__ WtH, unsigned short* __restrict__ WtL,
                       float* __restrict__ bias_cat,
                       const int* __restrict__ ei, int* __restrict__ deg, int E)
{
    const int b = blockIdx.x;
    const int t = threadIdx.x;
    if (b >= 5) {
        int e = (b - 5) * 256 + t;
        if (e < E) atomicAdd(&deg[ei[E + e]], 1);   // dst row
        return;
    }
    const int p = b;
    const float* src = (p == 0) ? Wq : (p == 1) ? Wk : (p == 2) ? Wv : (p == 3) ? Wsk : Wo;
    unsigned short* dh = WtH + (size_t)p * 16384;
    unsigned short* dl = WtL + (size_t)p * 16384;
#pragma unroll
    for (int j = 0; j < 64; ++j) {
        int o = t + j * 256;            // o = c*128 + k
        int c = o >> 7, k = o & 127;
        float v;
        if (p < 4) {
            int h = c >> 4, d = c & 15;
            v = src[(size_t)h * 2048 + (size_t)k * 16 + d];
        } else {
            v = src[(size_t)k * 128 + c];
        }
        unsigned short hi = f2bf_rne(v);
        unsigned short lo = f2bf_rne(v - bf2f(hi));
        dh[o] = hi; dl[o] = lo;
    }
    if (p < 4 && t < 128) {
        const float* bb = (p == 0) ? bq : (p == 1) ? bk : (p == 2) ? bv : bsk;
        bias_cat[p * 128 + t] = bb[t];
    }
}

// ---------- proj GEMM (split-bf16 MFMA): q, skip -> fp32; k,v -> packed bf16 kv ----------
// grid (ceil(N/128), 4); block 256 = 4 waves. Tile 128 rows x 128 cols, K=128.
__global__ __launch_bounds__(256)
void gemm_proj_kernel(const float* __restrict__ A,
                      const unsigned short* __restrict__ WtH_base,
                      const unsigned short* __restrict__ WtL_base,
                      const float* __restrict__ bias_cat,
                      float* __restrict__ qout, float* __restrict__ skipout,
                      unsigned short* __restrict__ kvout, int N)
{
    __shared__ unsigned short AhS[128 * 128];
    __shared__ unsigned short AlS[128 * 128];
    const int t = threadIdx.x;
    const int p = blockIdx.y;           // 0=q 1=k 2=v 3=skip
    const int r0 = blockIdx.x * 128;
    const unsigned short* BtH = WtH_base + (size_t)p * 16384;
    const unsigned short* BtL = WtL_base + (size_t)p * 16384;
    const float* bias = bias_cat + (size_t)p * 128;

#pragma unroll
    for (int j = 0; j < 16; ++j) {
        int f = t + j * 256;
        int row = f >> 5;
        int col4 = (f & 31) << 2;
        float4 v = make_float4(0.f, 0.f, 0.f, 0.f);
        int gr = r0 + row;
        if (gr < N) v = *reinterpret_cast<const float4*>(A + (size_t)gr * 128 + col4);
        ushort4 hi, lo;
        hi.x = f2bf_rne(v.x); lo.x = f2bf_rne(v.x - bf2f(hi.x));
        hi.y = f2bf_rne(v.y); lo.y = f2bf_rne(v.y - bf2f(hi.y));
        hi.z = f2bf_rne(v.z); lo.z = f2bf_rne(v.z - bf2f(hi.z));
        hi.w = f2bf_rne(v.w); lo.w = f2bf_rne(v.w - bf2f(hi.w));
        int byte = (col4 * 2) ^ ((row & 7) << 4);
        *reinterpret_cast<ushort4*>((char*)AhS + row * 256 + byte) = hi;
        *reinterpret_cast<ushort4*>((char*)AlS + row * 256 + byte) = lo;
    }
    __syncthreads();

    const int lane = t & 63;
    const int w = t >> 6;
    const int wrow0 = w * 32;
    const int lr = lane & 15;
    const int lk = lane >> 4;

    f32x4 acc[2][8];
#pragma unroll
    for (int mi = 0; mi < 2; ++mi)
#pragma unroll
        for (int ni = 0; ni < 8; ++ni) acc[mi][ni] = (f32x4){0.f, 0.f, 0.f, 0.f};

#pragma unroll
    for (int ks = 0; ks < 4; ++ks) {
        bf16x8 ah[2], al[2];
#pragma unroll
        for (int mi = 0; mi < 2; ++mi) {
            int row = wrow0 + mi * 16 + lr;
            int byte = (ks * 64 + lk * 16) ^ ((row & 7) << 4);
            ah[mi] = *reinterpret_cast<const bf16x8*>((const char*)AhS + row * 256 + byte);
            al[mi] = *reinterpret_cast<const bf16x8*>((const char*)AlS + row * 256 + byte);
        }
        bf16x8 bh[8], bl[8];
#pragma unroll
        for (int ni = 0; ni < 8; ++ni) {
            int c = ni * 16 + lr;
            size_t goff = (size_t)c * 128 + ks * 32 + lk * 8;
            bh[ni] = *reinterpret_cast<const bf16x8*>(BtH + goff);
            bl[ni] = *reinterpret_cast<const bf16x8*>(BtL + goff);
        }
#pragma unroll
        for (int mi = 0; mi < 2; ++mi)
#pragma unroll
            for (int ni = 0; ni < 8; ++ni) {
                acc[mi][ni] = __builtin_amdgcn_mfma_f32_16x16x32_bf16(ah[mi], bh[ni], acc[mi][ni], 0, 0, 0);
                acc[mi][ni] = __builtin_amdgcn_mfma_f32_16x16x32_bf16(ah[mi], bl[ni], acc[mi][ni], 0, 0, 0);
                acc[mi][ni] = __builtin_amdgcn_mfma_f32_16x16x32_bf16(al[mi], bh[ni], acc[mi][ni], 0, 0, 0);
            }
    }

    if (p == 0 || p == 3) {
        float* outp = (p == 0) ? qout : skipout;
#pragma unroll
        for (int mi = 0; mi < 2; ++mi)
#pragma unroll
            for (int ni = 0; ni < 8; ++ni) {
                int col = ni * 16 + lr;
                float bc = bias[col];
                int rowbase = wrow0 + mi * 16 + lk * 4;
#pragma unroll
                for (int r = 0; r < 4; ++r) {
                    int gr = r0 + rowbase + r;
                    if (gr < N) outp[(size_t)gr * 128 + col] = acc[mi][ni][r] + bc;
                }
            }
    } else {
        const int slot = (p == 1) ? 0 : 2;   // k -> shorts 0,1 ; v -> shorts 2,3
#pragma unroll
        for (int mi = 0; mi < 2; ++mi)
#pragma unroll
            for (int ni = 0; ni < 8; ++ni) {
                int col = ni * 16 + lr;
                float bc = bias[col];
                int sidx = 4 * (col >> 1) + (col & 1) + slot;
                int rowbase = wrow0 + mi * 16 + lk * 4;
#pragma unroll
                for (int r = 0; r < 4; ++r) {
                    int gr = r0 + rowbase + r;
                    if (gr < N) kvout[(size_t)gr * 256 + sidx] = f2bf_rne(acc[mi][ni][r] + bc);
                }
            }
    }
}

// ---------- out GEMM + residual + fused LayerNorm ----------
// grid (ceil(N/128)); block 256 = 4 waves. Each wave owns complete rows -> in-wave LN.
__global__ __launch_bounds__(256)
void gemm_out_ln_kernel(const float* __restrict__ A,
                        const unsigned short* __restrict__ BtH,
                        const unsigned short* __restrict__ BtL,
                        const float* __restrict__ bo,
                        const float* __restrict__ res,
                        const float* __restrict__ gamma,
                        const float* __restrict__ beta,
                        float* __restrict__ out, int N)
{
    __shared__ unsigned short AhS[128 * 128];
    __shared__ unsigned short AlS[128 * 128];
    const int t = threadIdx.x;
    const int r0 = blockIdx.x * 128;

#pragma unroll
    for (int j = 0; j < 16; ++j) {
        int f = t + j * 256;
        int row = f >> 5;
        int col4 = (f & 31) << 2;
        float4 v = make_float4(0.f, 0.f, 0.f, 0.f);
        int gr = r0 + row;
        if (gr < N) v = *reinterpret_cast<const float4*>(A + (size_t)gr * 128 + col4);
        ushort4 hi, lo;
        hi.x = f2bf_rne(v.x); lo.x = f2bf_rne(v.x - bf2f(hi.x));
        hi.y = f2bf_rne(v.y); lo.y = f2bf_rne(v.y - bf2f(hi.y));
        hi.z = f2bf_rne(v.z); lo.z = f2bf_rne(v.z - bf2f(hi.z));
        hi.w = f2bf_rne(v.w); lo.w = f2bf_rne(v.w - bf2f(hi.w));
        int byte = (col4 * 2) ^ ((row & 7) << 4);
        *reinterpret_cast<ushort4*>((char*)AhS + row * 256 + byte) = hi;
        *reinterpret_cast<ushort4*>((char*)AlS + row * 256 + byte) = lo;
    }
    __syncthreads();

    const int lane = t & 63;
    const int w = t >> 6;
    const int wrow0 = w * 32;
    const int lr = lane & 15;
    const int lk = lane >> 4;

    f32x4 acc[2][8];
#pragma unroll
    for (int mi = 0; mi < 2; ++mi)
#pragma unroll
        for (int ni = 0; ni < 8; ++ni) acc[mi][ni] = (f32x4){0.f, 0.f, 0.f, 0.f};

#pragma unroll
    for (int ks = 0; ks < 4; ++ks) {
        bf16x8 ah[2], al[2];
#pragma unroll
        for (int mi = 0; mi < 2; ++mi) {
            int row = wrow0 + mi * 16 + lr;
            int byte = (ks * 64 + lk * 16) ^ ((row & 7) << 4);
            ah[mi] = *reinterpret_cast<const bf16x8*>((const char*)AhS + row * 256 + byte);
            al[mi] = *reinterpret_cast<const bf16x8*>((const char*)AlS + row * 256 + byte);
        }
        bf16x8 bh[8], bl[8];
#pragma unroll
        for (int ni = 0; ni < 8; ++ni) {
            int c = ni * 16 + lr;
            size_t goff = (size_t)c * 128 + ks * 32 + lk * 8;
            bh[ni] = *reinterpret_cast<const bf16x8*>(BtH + goff);
            bl[ni] = *reinterpret_cast<const bf16x8*>(BtL + goff);
        }
#pragma unroll
        for (int mi = 0; mi < 2; ++mi)
#pragma unroll
            for (int ni = 0; ni < 8; ++ni) {
                acc[mi][ni] = __builtin_amdgcn_mfma_f32_16x16x32_bf16(ah[mi], bh[ni], acc[mi][ni], 0, 0, 0);
                acc[mi][ni] = __builtin_amdgcn_mfma_f32_16x16x32_bf16(ah[mi], bl[ni], acc[mi][ni], 0, 0, 0);
                acc[mi][ni] = __builtin_amdgcn_mfma_f32_16x16x32_bf16(al[mi], bh[ni], acc[mi][ni], 0, 0, 0);
            }
    }

    // epilogue: val = acc + bo + res; per-row LN via 16-lane shfl reduction; write out
#pragma unroll
    for (int mi = 0; mi < 2; ++mi) {
#pragma unroll
        for (int ni = 0; ni < 8; ++ni) {
            int col = ni * 16 + lr;
            float bc = bo[col];
            int rowbase = wrow0 + mi * 16 + lk * 4;
#pragma unroll
            for (int r = 0; r < 4; ++r) {
                int gr = r0 + rowbase + r;
                float rv = (gr < N) ? res[(size_t)gr * 128 + col] : 0.f;
                acc[mi][ni][r] += bc + rv;
            }
        }
#pragma unroll
        for (int r = 0; r < 4; ++r) {
            float s = 0.f, sq = 0.f;
#pragma unroll
            for (int ni = 0; ni < 8; ++ni) {
                float v = acc[mi][ni][r];
                s += v; sq += v * v;
            }
#pragma unroll
            for (int mk = 1; mk < 16; mk <<= 1) {
                s  += __shfl_xor(s, mk);
                sq += __shfl_xor(sq, mk);
            }
            float mean = s * (1.0f / 128.0f);
            float var  = sq * (1.0f / 128.0f) - mean * mean;
            float inv  = rsqrtf(var + 1e-5f);
            int gr = r0 + wrow0 + mi * 16 + lk * 4 + r;
            if (gr < N) {
#pragma unroll
                for (int ni = 0; ni < 8; ++ni) {
                    int col = ni * 16 + lr;
                    out[(size_t)gr * 128 + col] =
                        (acc[mi][ni][r] - mean) * inv * gamma[col] + beta[col];
                }
            }
        }
    }
}

// ---------------- exclusive scan (single block, shfl-based) ----------------
__global__ __launch_bounds__(1024)
void scan_kernel(const int* __restrict__ deg, int* __restrict__ offs,
                 int* __restrict__ cursor, int N)
{
    __shared__ int wsum[16];
    __shared__ int chunk_total_s;
    const int t = threadIdx.x;
    const int lane = t & 63, wid = t >> 6;
    int running = 0;
    for (int base = 0; base < N; base += 4096) {
        int v[4];
        int idx = base + t * 4;
#pragma unroll
        for (int j = 0; j < 4; ++j) { int i = idx + j; v[j] = (i < N) ? deg[i] : 0; }
        int ls = v[0] + v[1] + v[2] + v[3];
        int inc = ls;
#pragma unroll
        for (int off = 1; off < 64; off <<= 1) {
            int y = __shfl_up(inc, off);
            if (lane >= off) inc += y;
        }
        if (lane == 63) wsum[wid] = inc;
        __syncthreads();
        if (t < 16) {
            int winc = wsum[t];
            for (int off = 1; off < 16; off <<= 1) {
                int y = __shfl_up(winc, off);
                if (t >= off) winc += y;
            }
            wsum[t] = winc;
            if (t == 15) chunk_total_s = winc;
        }
        __syncthreads();
        int wexcl = (wid == 0) ? 0 : wsum[wid - 1];
        int texcl = running + wexcl + (inc - ls);
        int pre = 0;
#pragma unroll
        for (int j = 0; j < 4; ++j) {
            int i = idx + j;
            if (i < N) { offs[i] = texcl + pre; cursor[i] = texcl + pre; }
            pre += v[j];
        }
        running += chunk_total_s;
        __syncthreads();
    }
    if (t == 0) offs[N] = running;
}

// ---------------- scatter edges into CSR (packed int2 {src, ea}) ----------------
__global__ void scatter_kernel(const int* __restrict__ ei, const float* __restrict__ ea,
                               int* __restrict__ cursor, int2* __restrict__ csr, int E)
{
    int e = blockIdx.x * 256 + threadIdx.x;
    if (e < E) {
        int s = ei[e], d = ei[E + e];
        int pos = atomicAdd(&cursor[d], 1);
        csr[pos] = make_int2(s, __float_as_int(ea[e]));
    }
}

// ---------------- per-node online-softmax attention + aggregation ----------------
// one wave per node: 64 lanes = 8 heads x 8 lanes, 2 dims per lane.
// kv gather: one 8B bf16x4 load per lane per edge (contiguous 512B row per wave).
// depth-2 software pipeline: csr prefetched 2 ahead, kv gather 2 ahead.
__global__ __launch_bounds__(256)
void agg_kernel(const float* __restrict__ qb, const float* __restrict__ sb,
                const unsigned short* __restrict__ kvb,
                const int* __restrict__ offs, const int2* __restrict__ csr,
                const float* __restrict__ We, float* __restrict__ heads_cat, int N)
{
    const int lane = threadIdx.x & 63;
    const int node = blockIdx.x * 4 + (threadIdx.x >> 6);
    if (node >= N) return;

    const float2 q2  = *reinterpret_cast<const float2*>(qb + (size_t)node * 128 + 2 * lane);
    const float2 we2 = *reinterpret_cast<const float2*>(We + 2 * lane);

    float m = -__builtin_huge_valf();
    float ssum = 0.f, a0 = 0.f, a1 = 0.f;
    const int e0 = offs[node], e1 = offs[node + 1];

    int2 ec0, ec1, ec2;
    ushort4 g0, g1;
    if (e0 < e1)     ec0 = csr[e0];
    if (e0 + 1 < e1) ec1 = csr[e0 + 1];
    if (e0 < e1)     g0  = *reinterpret_cast<const ushort4*>(kvb + (size_t)ec0.x * 256 + 4 * lane);
    if (e0 + 1 < e1) g1  = *reinterpret_cast<const ushort4*>(kvb + (size_t)ec1.x * 256 + 4 * lane);

    for (int i = e0; i < e1; ++i) {
        // prefetch: csr 2 ahead, gather for i+1 was issued last iter; issue gather i+2's csr & i+1 handled
        if (i + 2 < e1) ec2 = csr[i + 2];
        // process edge i with (ec0, g0)
        const float eav = __int_as_float(ec0.y);
        float k0 = bf2f(g0.x), k1 = bf2f(g0.y);
        float v0 = bf2f(g0.z), v1 = bf2f(g0.w);
        float ke0 = k0 + eav * we2.x;
        float ke1 = k1 + eav * we2.y;
        float dot = q2.x * ke0 + q2.y * ke1;
        dot += __shfl_xor(dot, 1);
        dot += __shfl_xor(dot, 2);
        dot += __shfl_xor(dot, 4);
        float alpha = dot * 0.25f;               // 1/sqrt(16)
        float nm = fmaxf(m, alpha);
        float sc = __expf(m - nm);
        float pv = __expf(alpha - nm);
        ssum = ssum * sc + pv;
        a0 = a0 * sc + pv * (v0 + eav * we2.x);
        a1 = a1 * sc + pv * (v1 + eav * we2.y);
        m = nm;
        // rotate pipeline; issue gather for i+2
        ec0 = ec1; g0 = g1;
        ec1 = ec2;
        if (i + 2 < e1) g1 = *reinterpret_cast<const ushort4*>(kvb + (size_t)ec1.x * 256 + 4 * lane);
    }

    float inv = 1.0f / fmaxf(ssum, 1e-16f);
    const float2 sk = *reinterpret_cast<const float2*>(sb + (size_t)node * 128 + 2 * lane);
    float2 o;
    o.x = a0 * inv + sk.x;
    o.y = a1 * inv + sk.y;
    *reinterpret_cast<float2*>(heads_cat + (size_t)node * 128 + 2 * lane) = o;
}

extern "C" void kernel_launch(void* const* d_in, const int* in_sizes, int n_in,
                              void* d_out, int out_size, void* d_ws, size_t ws_size,
                              hipStream_t stream)
{
    const float* x    = (const float*)d_in[0];
    const int*   ei   = (const int*)d_in[1];
    const float* ea   = (const float*)d_in[2];
    const float* Wq   = (const float*)d_in[3];
    const float* bq   = (const float*)d_in[4];
    const float* Wk   = (const float*)d_in[5];
    const float* bk   = (const float*)d_in[6];
    const float* Wv   = (const float*)d_in[7];
    const float* bv   = (const float*)d_in[8];
    const float* We   = (const float*)d_in[9];
    const float* Wsk  = (const float*)d_in[10];
    const float* bsk  = (const float*)d_in[11];
    const float* Wo   = (const float*)d_in[12];
    const float* bo   = (const float*)d_in[13];
    const float* gamma= (const float*)d_in[14];
    const float* beta = (const float*)d_in[15];
    const int N = in_sizes[0] / 128;
    const int E = in_sizes[1] / 2;
    float* out = (float*)d_out;

    char* w = (char*)d_ws;
    float* qarr      = (float*)w; w += (size_t)N * 128 * sizeof(float);
    float* skiparr   = (float*)w; w += (size_t)N * 128 * sizeof(float);
    unsigned short* kv = (unsigned short*)w; w += (size_t)N * 256 * sizeof(unsigned short);
    float* heads_cat = (float*)w; w += (size_t)N * 128 * sizeof(float);
    int*   deg       = (int*)w;   w += ((size_t)N + 16) * sizeof(int);
    int*   offs      = (int*)w;   w += ((size_t)N + 16) * sizeof(int);
    int*   cursor    = (int*)w;   w += ((size_t)N + 16) * sizeof(int);
    int2*  csr       = (int2*)w;  w += (size_t)E * sizeof(int2);
    unsigned short* WtH = (unsigned short*)w; w += (size_t)5 * 16384 * sizeof(unsigned short);
    unsigned short* WtL = (unsigned short*)w; w += (size_t)5 * 16384 * sizeof(unsigned short);
    float* bias_cat  = (float*)w; w += 4 * 128 * sizeof(float);

    hipMemsetAsync(deg, 0, (size_t)N * sizeof(int), stream);

    const int cntBlocks = (E + 255) / 256;
    prep_count_kernel<<<5 + cntBlocks, 256, 0, stream>>>(Wq, Wk, Wv, Wsk, Wo, bq, bk, bv, bsk,
                                                         WtH, WtL, bias_cat, ei, deg, E);

    const int gx = (N + 127) / 128;
    dim3 gProj(gx, 4);
    gemm_proj_kernel<<<gProj, 256, 0, stream>>>(x, WtH, WtL, bias_cat, qarr, skiparr, kv, N);

    scan_kernel<<<1, 1024, 0, stream>>>(deg, offs, cursor, N);
    scatter_kernel<<<(E + 255) / 256, 256, 0, stream>>>(ei, ea, cursor, csr, E);
    agg_kernel<<<(N + 3) / 4, 256, 0, stream>>>(qarr, skiparr, kv, offs, csr, We, heads_cat, N);

    gemm_out_ln_kernel<<<gx, 256, 0, stream>>>(heads_cat, WtH + (size_t)4 * 16384, WtL + (size_t)4 * 16384,
                                               bo, x, gamma, beta, out, N);
}